// Round 5
// baseline (3242.620 us; speedup 1.0000x reference)
//
#include <hip/hip_runtime.h>

using u16 = unsigned short;
using u32 = unsigned int;

#define QSTEP (2.0f / 255.0f)
#define WINSZ 256

__device__ __forceinline__ float b2f(u16 u) {
  u32 v = ((u32)u) << 16;
  return __builtin_bit_cast(float, v);
}
// dtype-dispatching input load: flag=1 -> bf16, flag=0 -> fp32
__device__ __forceinline__ float ldin(const void* p, long i, int f) {
  return f ? b2f(((const u16*)p)[i]) : ((const float*)p)[i];
}
__device__ __forceinline__ float quantize(float v) {
  v = fminf(fmaxf(v, -1.0f), 1.0f);
  return QSTEP * rintf(v / QSTEP);
}

// ---- per-buffer dtype detect: flag=1 if bf16, 0 if fp32 ----
__global__ __launch_bounds__(256) void detect_k(const u16* __restrict__ x, int* flag) {
  __shared__ int cnt;
  if (threadIdx.x == 0) cnt = 0;
  __syncthreads();
  int c = 0;
#pragma unroll
  for (int i = 0; i < 8; i++) {
    const float v = fabsf(b2f(x[threadIdx.x * 8 + i]));
    if (v > 1e-5f && v < 1e3f) c++;
  }
  atomicAdd(&cnt, c);
  __syncthreads();
  if (threadIdx.x == 0) *flag = (cnt > 1536) ? 1 : 0;  // bf16 ~99.9%, fp32 ~55%
}

// ---- qkv = x @ w_attn, clip+quantize, split into qf/kf/vf [T][C] fp32 ----
__global__ __launch_bounds__(256) void qkv_naive(const void* __restrict__ x,
                                                 const int* __restrict__ fxp,
                                                 const void* __restrict__ w,
                                                 const int* __restrict__ fwp,
                                                 float* __restrict__ qf,
                                                 float* __restrict__ kf,
                                                 float* __restrict__ vf,
                                                 int C, int T) {
  const int C3 = 3 * C;
  const int fx = *fxp, fw = *fwp;
  const int c3 = blockIdx.x * 256 + threadIdx.x;
  if (c3 >= C3) return;
  const int t0 = blockIdx.y * 8;
  float acc[8] = {};
  for (int k = 0; k < C; k++) {
    const float wv = ldin(w, (long)k * C3 + c3, fw);
#pragma unroll
    for (int r = 0; r < 8; r++)
      if (t0 + r < T) acc[r] += ldin(x, (long)(t0 + r) * C + k, fx) * wv;
  }
  const int p = c3 / C, cc = c3 - p * C;
  float* dst = (p == 0) ? qf : ((p == 1) ? kf : vf);
#pragma unroll
  for (int r = 0; r < 8; r++)
    if (t0 + r < T) dst[(long)(t0 + r) * C + cc] = quantize(acc[r]);
}

// ---- attention, 32 queries per block, scalar math, fp32 S in LDS ----
__global__ __launch_bounds__(256) void attn_naive(const float* __restrict__ qf,
                                                  const float* __restrict__ kf,
                                                  const float* __restrict__ vf,
                                                  float* __restrict__ yq,
                                                  int C, int T) {
  __shared__ float S[32 * 321];  // 41 KB
  const int tid = threadIdx.x;
  const int h = blockIdx.y;
  const int i0 = blockIdx.x * 32;
  const int q = tid >> 3;   // 0..31
  const int seg = tid & 7;  // 8 threads per query
  const int i = i0 + q;
  const int j0 = i0 - 256;  // col c in [0,320) -> key j = j0 + c
  float* Srow = &S[q * 321];
  const bool live = (i < T);

  // phase A: scores -> mask -> scale -> quantize (masked = -inf)
  const float* qr = qf + (long)i * C + h * 64;
  for (int c = seg * 40; c < seg * 40 + 40; c++) {
    const int j = j0 + c;
    float sv = -INFINITY;
    if (live && j >= 0 && j <= i && j > i - WINSZ) {
      const float* kr = kf + (long)j * C + h * 64;
      float s = 0.0f;
      for (int d = 0; d < 64; d++) s += qr[d] * kr[d];
      sv = quantize(s * 0.125f);
    }
    Srow[c] = sv;
  }
  __syncthreads();

  // softmax across the row's 320 cols (8 threads per row)
  float m = -INFINITY;
  for (int c = seg * 40; c < seg * 40 + 40; c++) m = fmaxf(m, Srow[c]);
  m = fmaxf(m, __shfl_xor(m, 1));
  m = fmaxf(m, __shfl_xor(m, 2));
  m = fmaxf(m, __shfl_xor(m, 4));
  if (live) {
    float l = 0.0f;
    for (int c = seg * 40; c < seg * 40 + 40; c++) {
      const float e = expf(Srow[c] - m);
      l += e;
      Srow[c] = e;
    }
    l += __shfl_xor(l, 1);
    l += __shfl_xor(l, 2);
    l += __shfl_xor(l, 4);
    const float inv = 1.0f / l;
    for (int c = seg * 40; c < seg * 40 + 40; c++) Srow[c] *= inv;
  }
  __syncthreads();

  if (!live) return;
  // phase B: y = P @ V ; thread covers hd = seg*8 .. +8
  const int clo = (i0 < 256) ? (256 - i0) : 0;  // first c with j >= 0
  float acc[8] = {};
  for (int c = clo; c < 288; c++) {  // c>=288 -> j>i for all rows in block -> P=0
    const float pv = Srow[c];
    const float* vr = vf + (long)(j0 + c) * C + h * 64 + seg * 8;
#pragma unroll
    for (int u = 0; u < 8; u++) acc[u] += pv * vr[u];
  }
#pragma unroll
  for (int u = 0; u < 8; u++)
    yq[(long)i * C + h * 64 + seg * 8 + u] = quantize(acc[u]);
}

// ---- out = yq @ w_proj, store fp32 ----
__global__ __launch_bounds__(256) void proj_naive(const float* __restrict__ yq,
                                                  const void* __restrict__ w,
                                                  const int* __restrict__ fwp,
                                                  float* __restrict__ out,
                                                  int C, int T) {
  const int fw = *fwp;
  const int c = blockIdx.x * 256 + threadIdx.x;
  if (c >= C) return;
  const int t0 = blockIdx.y * 8;
  float acc[8] = {};
  for (int k = 0; k < C; k++) {
    const float wv = ldin(w, (long)k * C + c, fw);
#pragma unroll
    for (int r = 0; r < 8; r++)
      if (t0 + r < T) acc[r] += yq[(long)(t0 + r) * C + k] * wv;
  }
#pragma unroll
  for (int r = 0; r < 8; r++)
    if (t0 + r < T) out[(long)(t0 + r) * C + c] = acc[r];
}

// ---- launch ----
extern "C" void kernel_launch(void* const* d_in, const int* in_sizes, int n_in,
                              void* d_out, int out_size, void* d_ws, size_t ws_size,
                              hipStream_t stream) {
  // Structural binding: find pair with ratio 3 (w_attn = 3 * w_proj, w_proj = C*C);
  // the remaining tensor is x (= T*C). Robust to any input ordering.
  int ia = -1, ip = -1, ix = -1;
  for (int a = 0; a < n_in && ia < 0; a++)
    for (int b = 0; b < n_in; b++) {
      if (a == b) continue;
      if ((long)in_sizes[a] == 3L * in_sizes[b]) {
        long cc = 1;
        while (cc * cc < in_sizes[b]) cc++;
        if (cc * cc == in_sizes[b]) { ia = a; ip = b; break; }
      }
    }
  if (ia >= 0) {
    for (int t = 0; t < n_in; t++)
      if (t != ia && t != ip && in_sizes[t] > 1) { ix = t; break; }
  }
  int C = 1024, T = 2048;
  const void *px, *pwa, *pwp;
  if (ia >= 0 && ix >= 0) {
    pwa = d_in[ia]; pwp = d_in[ip]; px = d_in[ix];
    long cc = 1;
    while (cc * cc < in_sizes[ip]) cc++;
    C = (int)cc;
    T = in_sizes[ix] / C;
  } else {
    px = d_in[0]; pwa = d_in[1]; pwp = d_in[2];
  }
  const int H = C / 64;

  char* ws = (char*)d_ws;
  int* fx = (int*)ws;
  int* fwa = fx + 1;
  int* fwp = fx + 2;
  float* qf = (float*)(ws + (1u << 20));
  float* kf = qf + (long)T * C;
  float* vf = kf + (long)T * C;
  float* yq = vf + (long)T * C;

  detect_k<<<1, 256, 0, stream>>>((const u16*)px, fx);
  detect_k<<<1, 256, 0, stream>>>((const u16*)pwa, fwa);
  detect_k<<<1, 256, 0, stream>>>((const u16*)pwp, fwp);
  qkv_naive<<<dim3((3 * C + 255) / 256, (T + 7) / 8), 256, 0, stream>>>(px, fx, pwa, fwa, qf,
                                                                        kf, vf, C, T);
  attn_naive<<<dim3((T + 31) / 32, H), 256, 0, stream>>>(qf, kf, vf, yq, C, T);
  proj_naive<<<dim3((C + 255) / 256, (T + 7) / 8), 256, 0, stream>>>(yq, pwp, fwp,
                                                                     (float*)d_out, C, T);
}

// Round 6
// 182.696 us; speedup vs baseline: 17.7487x; 17.7487x over previous
//
#include <hip/hip_runtime.h>

using u16 = unsigned short;
using u32 = unsigned int;

typedef __bf16 bf16x8 __attribute__((ext_vector_type(8)));
typedef float f32x4 __attribute__((ext_vector_type(4)));

#define T_SEQ 2048
#define NC 1024
#define HDIM 64
#define WINSZ 256
#define QSTEP (2.0f / 255.0f)

__device__ __forceinline__ float b2f(u16 u) {
  u32 v = ((u32)u) << 16;
  return __builtin_bit_cast(float, v);
}
__device__ __forceinline__ u16 f2b(float f) {
  u32 x = __builtin_bit_cast(u32, f);
  u32 r = (x + 0x7fffu + ((x >> 16) & 1u)) >> 16;  // RNE
  return (u16)r;
}
__device__ __forceinline__ float quantize(float v) {
  v = fminf(fmaxf(v, -1.0f), 1.0f);
  return QSTEP * rintf(v / QSTEP);
}
__device__ __forceinline__ void cp16(const void* g, void* l) {
  __builtin_amdgcn_global_load_lds((__attribute__((address_space(1))) void*)g,
                                   (__attribute__((address_space(3))) void*)l, 16, 0, 0);
}

// ---- per-buffer dtype detect (3 blocks, one per buffer): flag=1 bf16, 0 fp32 ----
__global__ __launch_bounds__(256) void detect3(const u16* __restrict__ a,
                                               const u16* __restrict__ b,
                                               const u16* __restrict__ c, int* flags) {
  const u16* p = (blockIdx.x == 0) ? a : ((blockIdx.x == 1) ? b : c);
  __shared__ int cnt;
  if (threadIdx.x == 0) cnt = 0;
  __syncthreads();
  int n = 0;
#pragma unroll
  for (int i = 0; i < 8; i++) {
    const float v = fabsf(b2f(p[threadIdx.x * 8 + i]));
    if (v > 1e-5f && v < 1e3f) n++;
  }
  atomicAdd(&cnt, n);
  __syncthreads();
  if (threadIdx.x == 0) flags[blockIdx.x] = (cnt > 1536) ? 1 : 0;
}

// ---- convert x -> bf16 (vectorized x4) ----
__global__ __launch_bounds__(256) void cvt_x(const void* __restrict__ in, u16* __restrict__ outp,
                                             const int* __restrict__ flag, int n4) {
  const int i = blockIdx.x * 256 + threadIdx.x;
  if (i >= n4) return;
  if (*flag) {
    ((ushort4*)outp)[i] = ((const ushort4*)in)[i];
  } else {
    const float4 v = ((const float4*)in)[i];
    ushort4 o;
    o.x = f2b(v.x); o.y = f2b(v.y); o.z = f2b(v.z); o.w = f2b(v.w);
    ((ushort4*)outp)[i] = o;
  }
}

// ---- convert + transpose: in[R][Cc] -> out[Cc][R] bf16 ----
__global__ __launch_bounds__(256) void transpose_k(const void* __restrict__ in,
                                                   u16* __restrict__ out,
                                                   const int* __restrict__ flag, int R, int Cc) {
  __shared__ u16 tile[64][65];
  const int tc = blockIdx.x * 64, tr = blockIdx.y * 64;
  const int lx = threadIdx.x & 63, ly = threadIdx.x >> 6;
  const int f = *flag;
#pragma unroll
  for (int r = ly; r < 64; r += 4) {
    const long idx = (long)(tr + r) * Cc + tc + lx;
    tile[r][lx] = f ? ((const u16*)in)[idx] : f2b(((const float*)in)[idx]);
  }
  __syncthreads();
#pragma unroll
  for (int r = ly; r < 64; r += 4) out[(tc + r) * R + tr + lx] = tile[lx][r];
}

// ---- 128x128 MFMA GEMM: C = A[Mx1024] * BT[Nx1024]^T (m97 2-barrier K-loop) ----
// MODE 0: fused clip+quantize, scatter q->o0[H][T][HD], k->o1[H][T][HD], v->o2[H][HD][T]
// MODE 1: plain fp32 store to of[M][NC]
template <int MODE>
__global__ __launch_bounds__(256, 2) void gemm128(const u16* __restrict__ A,
                                                  const u16* __restrict__ BT,
                                                  u16* __restrict__ o0, u16* __restrict__ o1,
                                                  u16* __restrict__ o2, float* __restrict__ of) {
  __shared__ __align__(16) u16 As[4096];  // [kb:4][row:128][8]
  __shared__ __align__(16) u16 Bs[4096];
  const int tid = threadIdx.x;
  const int lane = tid & 63;
  const int wave = tid >> 6;
  const int wr = wave >> 1, wc = wave & 1;
  const int ln15 = lane & 15, lq = lane >> 4;
  const int m0 = blockIdx.y * 128, n0 = blockIdx.x * 128;

  const int srow = tid & 127, skb = tid >> 7;
  const u16* ag0 = A + (m0 + srow) * NC + skb * 8;
  const u16* bg0 = BT + (n0 + srow) * NC + skb * 8;
  u16* lA0 = &As[tid * 8];
  u16* lA1 = &As[(tid + 256) * 8];
  u16* lB0 = &Bs[tid * 8];
  u16* lB1 = &Bs[(tid + 256) * 8];

  f32x4 acc[4][4] = {};

  for (int kt = 0; kt < NC; kt += 32) {
    cp16(ag0 + kt, lA0);
    cp16(ag0 + kt + 16, lA1);
    cp16(bg0 + kt, lB0);
    cp16(bg0 + kt + 16, lB1);
    __syncthreads();  // staging complete (barrier drains vmcnt)
    bf16x8 af[4], bfr[4];
#pragma unroll
    for (int r = 0; r < 4; r++)
      af[r] = *(const bf16x8*)&As[(lq * 128 + wr * 64 + r * 16 + ln15) * 8];
#pragma unroll
    for (int c = 0; c < 4; c++)
      bfr[c] = *(const bf16x8*)&Bs[(lq * 128 + wc * 64 + c * 16 + ln15) * 8];
#pragma unroll
    for (int r = 0; r < 4; r++)
#pragma unroll
      for (int c = 0; c < 4; c++)
        acc[r][c] = __builtin_amdgcn_mfma_f32_16x16x32_bf16(af[r], bfr[c], acc[r][c], 0, 0, 0);
    __syncthreads();  // all reads done before next tile's cp16 overwrites
  }

  if (MODE == 0) {
#pragma unroll
    for (int c = 0; c < 4; c++) {
      const int gcol = n0 + wc * 64 + c * 16 + ln15;
      const int p = gcol >> 10;  // 0=q, 1=k, 2=v
      const int h = (gcol & 1023) >> 6;
      const int hd = gcol & 63;
#pragma unroll
      for (int r = 0; r < 4; r++) {
        const int rbase = m0 + wr * 64 + r * 16 + lq * 4;
#pragma unroll
        for (int g = 0; g < 4; g++) {
          const u16 b = f2b(quantize(acc[r][c][g]));
          const int row = rbase + g;
          if (p == 0)      o0[(h * T_SEQ + row) * HDIM + hd] = b;
          else if (p == 1) o1[(h * T_SEQ + row) * HDIM + hd] = b;
          else             o2[(h * HDIM + hd) * T_SEQ + row] = b;
        }
      }
    }
  } else {
#pragma unroll
    for (int r = 0; r < 4; r++)
#pragma unroll
      for (int g = 0; g < 4; g++) {
        const int row = m0 + wr * 64 + r * 16 + lq * 4 + g;
#pragma unroll
        for (int c = 0; c < 4; c++) of[(long)row * NC + n0 + wc * 64 + c * 16 + ln15] = acc[r][c][g];
      }
  }
}

// ---- attention: one block per (64 queries, head); MFMA QK^T and PV ----
__global__ __launch_bounds__(256) void attn_k(const u16* __restrict__ qh,
                                              const u16* __restrict__ kh,
                                              const u16* __restrict__ vt,
                                              u16* __restrict__ yq) {
  __shared__ __align__(16) u16 S[64 * 328];
  const int tid = threadIdx.x;
  const int lane = tid & 63;
  const int wave = tid >> 6;
  const int ln15 = lane & 15, lq = lane >> 4;
  const int i0 = blockIdx.x * 64;
  const int h = blockIdx.y;
  const int j0 = i0 - 256;  // key col c in [0,320) -> j = j0 + c

  const u16* qb = qh + (h * T_SEQ + i0) * HDIM;
  const u16* kb = kh + h * T_SEQ * HDIM;

  bf16x8 qf[4][2];
#pragma unroll
  for (int r = 0; r < 4; r++) {
    qf[r][0] = *(const bf16x8*)&qb[(r * 16 + ln15) * HDIM + lq * 8];
    qf[r][1] = *(const bf16x8*)&qb[(r * 16 + ln15) * HDIM + 32 + lq * 8];
  }

  // phase 1: scores -> mask -> scale -> quantize -> S (masked = -inf)
  for (int ct = wave; ct < 20; ct += 4) {
    const int jt = j0 + ct * 16;
    bf16x8 kf0 = {}, kf1 = {};
    if (jt >= 0) {
      kf0 = *(const bf16x8*)&kb[(jt + ln15) * HDIM + lq * 8];
      kf1 = *(const bf16x8*)&kb[(jt + ln15) * HDIM + 32 + lq * 8];
    }
#pragma unroll
    for (int rt = 0; rt < 4; rt++) {
      const bool skip = (ct < rt) || (ct > rt + 16) || (jt < 0);
      f32x4 s = {0.f, 0.f, 0.f, 0.f};
      if (!skip) {
        s = __builtin_amdgcn_mfma_f32_16x16x32_bf16(qf[rt][0], kf0, s, 0, 0, 0);
        s = __builtin_amdgcn_mfma_f32_16x16x32_bf16(qf[rt][1], kf1, s, 0, 0, 0);
      }
      const int j = jt + ln15;
#pragma unroll
      for (int g = 0; g < 4; g++) {
        const int i = i0 + rt * 16 + lq * 4 + g;
        float v = -INFINITY;
        if (!skip && j <= i && j > i - WINSZ) v = quantize(s[g] * 0.125f);
        S[(rt * 16 + lq * 4 + g) * 328 + ct * 16 + ln15] = f2b(v);
      }
    }
  }
  __syncthreads();

  // phase 2: softmax per row over 320 cols (4 threads/row)
  {
    const int r = tid >> 2;
    u16* Srow = &S[r * 328 + (tid & 3) * 80];
    float m = -INFINITY;
    for (int c = 0; c < 80; c++) m = fmaxf(m, b2f(Srow[c]));
    m = fmaxf(m, __shfl_xor(m, 1));
    m = fmaxf(m, __shfl_xor(m, 2));
    float l = 0.0f;
    float e[80];
    for (int c = 0; c < 80; c++) {
      e[c] = expf(b2f(Srow[c]) - m);
      l += e[c];
    }
    l += __shfl_xor(l, 1);
    l += __shfl_xor(l, 2);
    const float inv = 1.0f / l;
    for (int c = 0; c < 80; c++) Srow[c] = f2b(e[c] * inv);
  }
  __syncthreads();

  // phase 3: y = P @ V^T ; wave covers hd block = wave*16
  f32x4 acc[4] = {};
  const u16* vb = vt + (h * HDIM + wave * 16 + ln15) * T_SEQ;
  const int kk_lo = (i0 < 256) ? ((256 - i0) >> 5) : 0;  // skip j<0 chunks (P=0 there)
  for (int kk = kk_lo; kk < 10; kk++) {
    const int jb = j0 + kk * 32 + lq * 8;  // >= 0 by kk_lo
    const bf16x8 vf = *(const bf16x8*)&vb[jb];
#pragma unroll
    for (int rt = 0; rt < 4; rt++) {
      const bf16x8 pf = *(const bf16x8*)&S[(rt * 16 + ln15) * 328 + kk * 32 + lq * 8];
      acc[rt] = __builtin_amdgcn_mfma_f32_16x16x32_bf16(pf, vf, acc[rt], 0, 0, 0);
    }
  }
#pragma unroll
  for (int rt = 0; rt < 4; rt++)
#pragma unroll
    for (int g = 0; g < 4; g++) {
      const int i = i0 + rt * 16 + lq * 4 + g;
      yq[i * NC + h * HDIM + wave * 16 + ln15] = f2b(quantize(acc[rt][g]));
    }
}

// ---- launch ----
extern "C" void kernel_launch(void* const* d_in, const int* in_sizes, int n_in,
                              void* d_out, int out_size, void* d_ws, size_t ws_size,
                              hipStream_t stream) {
  // bind by element count (order-robust): x=2M, w_attn=3M, w_proj=1M
  const void *px = d_in[0], *pwa = d_in[1], *pwp = d_in[2];
  for (int i = 0; i < n_in; i++) {
    if (in_sizes[i] == 2048 * 1024) px = d_in[i];
    else if (in_sizes[i] == 3072 * 1024) pwa = d_in[i];
    else if (in_sizes[i] == 1024 * 1024) pwp = d_in[i];
  }

  char* ws = (char*)d_ws;
  int* flags = (int*)ws;                  // [3]: x, w_attn, w_proj
  u16* xb  = (u16*)(ws + (1u << 20));     // [2048][1024]  4 MB
  u16* wTa = (u16*)(ws + (5u << 20));     // [3072][1024]  6 MB
  u16* wTp = (u16*)(ws + (11u << 20));    // [1024][1024]  2 MB
  u16* qh  = (u16*)(ws + (13u << 20));    // [16][2048][64] 4 MB
  u16* kh  = (u16*)(ws + (17u << 20));    // 4 MB
  u16* vt  = (u16*)(ws + (21u << 20));    // [16][64][2048] 4 MB
  u16* yq  = (u16*)(ws + (25u << 20));    // [2048][1024]  4 MB

  detect3<<<3, 256, 0, stream>>>((const u16*)px, (const u16*)pwa, (const u16*)pwp, flags);
  cvt_x<<<2048, 256, 0, stream>>>(px, xb, flags + 0, T_SEQ * NC / 4);
  transpose_k<<<dim3(48, 16), 256, 0, stream>>>(pwa, wTa, flags + 1, 1024, 3072);
  transpose_k<<<dim3(16, 16), 256, 0, stream>>>(pwp, wTp, flags + 2, 1024, 1024);
  gemm128<0><<<dim3(24, 16), 256, 0, stream>>>(xb, wTa, qh, kh, vt, nullptr);
  attn_k<<<dim3(32, 16), 256, 0, stream>>>(qh, kh, vt, yq);
  gemm128<1><<<dim3(8, 16), 256, 0, stream>>>(yq, wTp, nullptr, nullptr, nullptr, (float*)d_out);
}

// Round 7
// 181.600 us; speedup vs baseline: 17.8558x; 1.0060x over previous
//
#include <hip/hip_runtime.h>

using u16 = unsigned short;
using u32 = unsigned int;

typedef __bf16 bf16x8 __attribute__((ext_vector_type(8)));
typedef float f32x4 __attribute__((ext_vector_type(4)));

#define T_SEQ 2048
#define NC 1024
#define HDIM 64
#define WINSZ 256
#define QSTEP (2.0f / 255.0f)

__device__ __forceinline__ float b2f(u16 u) {
  u32 v = ((u32)u) << 16;
  return __builtin_bit_cast(float, v);
}
__device__ __forceinline__ u16 f2b(float f) {
  u32 x = __builtin_bit_cast(u32, f);
  u32 r = (x + 0x7fffu + ((x >> 16) & 1u)) >> 16;  // RNE
  return (u16)r;
}
__device__ __forceinline__ float quantize(float v) {
  v = fminf(fmaxf(v, -1.0f), 1.0f);
  return QSTEP * rintf(v / QSTEP);
}
__device__ __forceinline__ void cp16(const void* g, void* l) {
  __builtin_amdgcn_global_load_lds((__attribute__((address_space(1))) void*)g,
                                   (__attribute__((address_space(3))) void*)l, 16, 0, 0);
}

// ---- per-buffer dtype detect (3 blocks): flag=1 bf16, 0 fp32 ----
__global__ __launch_bounds__(256) void detect3(const u16* __restrict__ a,
                                               const u16* __restrict__ b,
                                               const u16* __restrict__ c, int* flags) {
  const u16* p = (blockIdx.x == 0) ? a : ((blockIdx.x == 1) ? b : c);
  __shared__ int cnt;
  if (threadIdx.x == 0) cnt = 0;
  __syncthreads();
  int n = 0;
#pragma unroll
  for (int i = 0; i < 8; i++) {
    const float v = fabsf(b2f(p[threadIdx.x * 8 + i]));
    if (v > 1e-5f && v < 1e3f) n++;
  }
  atomicAdd(&cnt, n);
  __syncthreads();
  if (threadIdx.x == 0) flags[blockIdx.x] = (cnt > 1536) ? 1 : 0;
}

// ---- fused prep: z=0 transpose w_attn, z=1 transpose w_proj, z=2 convert x ----
__global__ __launch_bounds__(256) void prep_k(const void* __restrict__ x, u16* __restrict__ xb,
                                              const void* __restrict__ wa, u16* __restrict__ wTa,
                                              const void* __restrict__ wp, u16* __restrict__ wTp,
                                              const int* __restrict__ flags) {
  if (blockIdx.z == 2) {  // x: fp32/bf16 -> bf16 copy, vectorized x4
    const int f = flags[0];
    const int nb = gridDim.x * gridDim.y;
    const int bid = blockIdx.y * gridDim.x + blockIdx.x;
    const int n4 = T_SEQ * NC / 4;
    for (int i = bid * 256 + threadIdx.x; i < n4; i += nb * 256) {
      if (f) {
        ((ushort4*)xb)[i] = ((const ushort4*)x)[i];
      } else {
        const float4 v = ((const float4*)x)[i];
        ushort4 o;
        o.x = f2b(v.x); o.y = f2b(v.y); o.z = f2b(v.z); o.w = f2b(v.w);
        ((ushort4*)xb)[i] = o;
      }
    }
    return;
  }
  const int iswp = (blockIdx.z == 1);
  if (iswp && blockIdx.x >= 16) return;
  const void* in = iswp ? wp : wa;
  u16* out = iswp ? wTp : wTa;
  const int Cc = iswp ? 1024 : 3072;
  const int f = flags[iswp ? 2 : 1];
  __shared__ u16 tile[64][65];
  const int tc = blockIdx.x * 64, tr = blockIdx.y * 64;
  const int lx = threadIdx.x & 63, ly = threadIdx.x >> 6;
#pragma unroll
  for (int r = ly; r < 64; r += 4) {
    const long idx = (long)(tr + r) * Cc + tc + lx;
    tile[r][lx] = f ? ((const u16*)in)[idx] : f2b(((const float*)in)[idx]);
  }
  __syncthreads();
#pragma unroll
  for (int r = ly; r < 64; r += 4) out[(tc + r) * 1024 + tr + lx] = tile[lx][r];
}

// ---- 128x128 MFMA GEMM, BK=64, LDS double-buffer + fine-grained vmcnt barriers ----
// C = A[Mx1024] * BT[Nx1024]^T
// MODE 0: fused clip+quantize, scatter q->o0[H][T][HD], k->o1[H][T][HD], v->o2[H][HD][T]
// MODE 1: plain fp32 store to of[M][NC]
template <int MODE>
__global__ __launch_bounds__(256, 2) void gemm128(const u16* __restrict__ A,
                                                  const u16* __restrict__ BT,
                                                  u16* __restrict__ o0, u16* __restrict__ o1,
                                                  u16* __restrict__ o2, float* __restrict__ of) {
  __shared__ __align__(16) u16 As[2][8192];  // [kc:8][row:128][8]
  __shared__ __align__(16) u16 Bs[2][8192];
  const int tid = threadIdx.x;
  const int lane = tid & 63;
  const int wave = tid >> 6;
  const int wr = wave >> 1, wc = wave & 1;
  const int ln15 = lane & 15, lq = lane >> 4;
  const int m0 = blockIdx.y * 128, n0 = blockIdx.x * 128;

  // staging: 1024 16B-chunks per matrix per tile; 4 per thread. id -> kc=id>>7, row=id&127
  const u16* ag[4];
  const u16* bg[4];
  u16* la[2][4];
  u16* lb[2][4];
#pragma unroll
  for (int i = 0; i < 4; i++) {
    const int id = tid + i * 256;
    const int kc = id >> 7, row = id & 127;
    ag[i] = A + (m0 + row) * NC + kc * 8;
    bg[i] = BT + (n0 + row) * NC + kc * 8;
    la[0][i] = &As[0][id * 8];
    la[1][i] = &As[1][id * 8];
    lb[0][i] = &Bs[0][id * 8];
    lb[1][i] = &Bs[1][id * 8];
  }

  f32x4 acc[4][4] = {};

  // prologue: stage tile 0 (8 outstanding vm-ops per thread)
#pragma unroll
  for (int i = 0; i < 4; i++) {
    cp16(ag[i], la[0][i]);
    cp16(bg[i], lb[0][i]);
  }

#pragma unroll 1
  for (int it = 0; it < 16; ++it) {
    const int cur = it & 1;
    if (it < 15) {
      const int nxt = cur ^ 1;
      const int koff = (it + 1) * 64;
#pragma unroll
      for (int i = 0; i < 4; i++) {
        cp16(ag[i] + koff, la[nxt][i]);
        cp16(bg[i] + koff, lb[nxt][i]);
      }
      // wait for tile `it`'s 8 loads (oldest); keep tile it+1's 8 in flight
      asm volatile("s_waitcnt vmcnt(8)\n\ts_barrier" ::: "memory");
    } else {
      asm volatile("s_waitcnt vmcnt(0)\n\ts_barrier" ::: "memory");
    }
#pragma unroll
    for (int s = 0; s < 2; s++) {
      const int kc = s * 4 + lq;
      bf16x8 af[4], bfr[4];
#pragma unroll
      for (int r = 0; r < 4; r++)
        af[r] = *(const bf16x8*)&As[cur][(kc * 128 + wr * 64 + r * 16 + ln15) * 8];
#pragma unroll
      for (int c = 0; c < 4; c++)
        bfr[c] = *(const bf16x8*)&Bs[cur][(kc * 128 + wc * 64 + c * 16 + ln15) * 8];
#pragma unroll
      for (int r = 0; r < 4; r++)
#pragma unroll
        for (int c = 0; c < 4; c++)
          acc[r][c] = __builtin_amdgcn_mfma_f32_16x16x32_bf16(af[r], bfr[c], acc[r][c], 0, 0, 0);
    }
    // all waves' ds_reads of buf `cur` are complete (consumed by MFMA) before
    // anyone issues next iteration's cp16 into it
    asm volatile("s_barrier" ::: "memory");
  }

  if (MODE == 0) {
#pragma unroll
    for (int c = 0; c < 4; c++) {
      const int gcol = n0 + wc * 64 + c * 16 + ln15;
      const int p = gcol >> 10;  // 0=q, 1=k, 2=v
      const int h = (gcol & 1023) >> 6;
      const int hd = gcol & 63;
#pragma unroll
      for (int r = 0; r < 4; r++) {
        const int rbase = m0 + wr * 64 + r * 16 + lq * 4;
#pragma unroll
        for (int g = 0; g < 4; g++) {
          const u16 b = f2b(quantize(acc[r][c][g]));
          const int row = rbase + g;
          if (p == 0)      o0[(h * T_SEQ + row) * HDIM + hd] = b;
          else if (p == 1) o1[(h * T_SEQ + row) * HDIM + hd] = b;
          else             o2[(h * HDIM + hd) * T_SEQ + row] = b;
        }
      }
    }
  } else {
#pragma unroll
    for (int r = 0; r < 4; r++)
#pragma unroll
      for (int g = 0; g < 4; g++) {
        const int row = m0 + wr * 64 + r * 16 + lq * 4 + g;
#pragma unroll
        for (int c = 0; c < 4; c++)
          of[(long)row * NC + n0 + wc * 64 + c * 16 + ln15] = acc[r][c][g];
      }
  }
}

// ---- attention: one block per (64 queries, head); MFMA QK^T and PV ----
__global__ __launch_bounds__(256) void attn_k(const u16* __restrict__ qh,
                                              const u16* __restrict__ kh,
                                              const u16* __restrict__ vt,
                                              u16* __restrict__ yq) {
  __shared__ __align__(16) u16 S[64 * 328];
  const int tid = threadIdx.x;
  const int lane = tid & 63;
  const int wave = tid >> 6;
  const int ln15 = lane & 15, lq = lane >> 4;
  const int i0 = blockIdx.x * 64;
  const int h = blockIdx.y;
  const int j0 = i0 - 256;  // key col c in [0,320) -> j = j0 + c

  const u16* qb = qh + (h * T_SEQ + i0) * HDIM;
  const u16* kb = kh + h * T_SEQ * HDIM;

  bf16x8 qf[4][2];
#pragma unroll
  for (int r = 0; r < 4; r++) {
    qf[r][0] = *(const bf16x8*)&qb[(r * 16 + ln15) * HDIM + lq * 8];
    qf[r][1] = *(const bf16x8*)&qb[(r * 16 + ln15) * HDIM + 32 + lq * 8];
  }

  // phase 1: scores -> mask -> scale -> quantize -> S (masked = -inf)
  for (int ct = wave; ct < 20; ct += 4) {
    const int jt = j0 + ct * 16;
    bf16x8 kf0 = {}, kf1 = {};
    if (jt >= 0) {
      kf0 = *(const bf16x8*)&kb[(jt + ln15) * HDIM + lq * 8];
      kf1 = *(const bf16x8*)&kb[(jt + ln15) * HDIM + 32 + lq * 8];
    }
#pragma unroll
    for (int rt = 0; rt < 4; rt++) {
      const bool skip = (ct < rt) || (ct > rt + 16) || (jt < 0);
      f32x4 s = {0.f, 0.f, 0.f, 0.f};
      if (!skip) {
        s = __builtin_amdgcn_mfma_f32_16x16x32_bf16(qf[rt][0], kf0, s, 0, 0, 0);
        s = __builtin_amdgcn_mfma_f32_16x16x32_bf16(qf[rt][1], kf1, s, 0, 0, 0);
      }
      const int j = jt + ln15;
#pragma unroll
      for (int g = 0; g < 4; g++) {
        const int i = i0 + rt * 16 + lq * 4 + g;
        float v = -INFINITY;
        if (!skip && j <= i && j > i - WINSZ) v = quantize(s[g] * 0.125f);
        S[(rt * 16 + lq * 4 + g) * 328 + ct * 16 + ln15] = f2b(v);
      }
    }
  }
  __syncthreads();

  // phase 2: softmax per row over 320 cols (4 threads/row), no per-thread spill array
  {
    const int r = tid >> 2;
    u16* Srow = &S[r * 328 + (tid & 3) * 80];
    float m = -INFINITY;
    for (int c = 0; c < 80; c++) m = fmaxf(m, b2f(Srow[c]));
    m = fmaxf(m, __shfl_xor(m, 1));
    m = fmaxf(m, __shfl_xor(m, 2));
    float l = 0.0f;
    for (int c = 0; c < 80; c++) {
      const float e = __expf(b2f(Srow[c]) - m);
      l += e;
      Srow[c] = f2b(e);
    }
    l += __shfl_xor(l, 1);
    l += __shfl_xor(l, 2);
    const float inv = 1.0f / l;
    for (int c = 0; c < 80; c++) Srow[c] = f2b(b2f(Srow[c]) * inv);
  }
  __syncthreads();

  // phase 3: y = P @ V^T ; wave covers hd block = wave*16
  f32x4 acc[4] = {};
  const u16* vb = vt + (h * HDIM + wave * 16 + ln15) * T_SEQ;
  const int kk_lo = (i0 < 256) ? ((256 - i0) >> 5) : 0;  // skip j<0 chunks (P=0 there)
  for (int kk = kk_lo; kk < 10; kk++) {
    const int jb = j0 + kk * 32 + lq * 8;  // >= 0 by kk_lo
    const bf16x8 vf = *(const bf16x8*)&vb[jb];
#pragma unroll
    for (int rt = 0; rt < 4; rt++) {
      const bf16x8 pf = *(const bf16x8*)&S[(rt * 16 + ln15) * 328 + kk * 32 + lq * 8];
      acc[rt] = __builtin_amdgcn_mfma_f32_16x16x32_bf16(pf, vf, acc[rt], 0, 0, 0);
    }
  }
#pragma unroll
  for (int rt = 0; rt < 4; rt++)
#pragma unroll
    for (int g = 0; g < 4; g++) {
      const int i = i0 + rt * 16 + lq * 4 + g;
      yq[i * NC + h * HDIM + wave * 16 + ln15] = f2b(quantize(acc[rt][g]));
    }
}

// ---- launch ----
extern "C" void kernel_launch(void* const* d_in, const int* in_sizes, int n_in,
                              void* d_out, int out_size, void* d_ws, size_t ws_size,
                              hipStream_t stream) {
  // bind by element count (order-robust): x=2M, w_attn=3M, w_proj=1M
  const void *px = d_in[0], *pwa = d_in[1], *pwp = d_in[2];
  for (int i = 0; i < n_in; i++) {
    if (in_sizes[i] == 2048 * 1024) px = d_in[i];
    else if (in_sizes[i] == 3072 * 1024) pwa = d_in[i];
    else if (in_sizes[i] == 1024 * 1024) pwp = d_in[i];
  }

  char* ws = (char*)d_ws;
  int* flags = (int*)ws;                 // [3]: x, w_attn, w_proj
  u16* xb  = (u16*)(ws + (1u << 20));    // [2048][1024]  4 MB
  u16* wTa = (u16*)(ws + (5u << 20));    // [3072][1024]  6 MB
  u16* wTp = (u16*)(ws + (11u << 20));   // [1024][1024]  2 MB
  u16* qh  = (u16*)(ws + (13u << 20));   // [16][2048][64] 4 MB
  u16* kh  = (u16*)(ws + (17u << 20));   // 4 MB
  u16* vt  = (u16*)(ws + (21u << 20));   // [16][64][2048] 4 MB
  u16* yq  = (u16*)(ws + (25u << 20));   // [2048][1024]  4 MB

  detect3<<<3, 256, 0, stream>>>((const u16*)px, (const u16*)pwa, (const u16*)pwp, flags);
  prep_k<<<dim3(48, 16, 3), 256, 0, stream>>>(px, xb, pwa, wTa, pwp, wTp, flags);
  gemm128<0><<<dim3(24, 16), 256, 0, stream>>>(xb, wTa, qh, kh, vt, nullptr);
  attn_k<<<dim3(32, 16), 256, 0, stream>>>(qh, kh, vt, yq);
  gemm128<1><<<dim3(8, 16), 256, 0, stream>>>(yq, wTp, nullptr, nullptr, nullptr, (float*)d_out);
}

// Round 8
// 170.272 us; speedup vs baseline: 19.0438x; 1.0665x over previous
//
#include <hip/hip_runtime.h>

using u16 = unsigned short;
using u32 = unsigned int;

typedef __bf16 bf16x8 __attribute__((ext_vector_type(8)));
typedef float f32x4 __attribute__((ext_vector_type(4)));

#define T_SEQ 2048
#define NC 1024
#define HDIM 64
#define WINSZ 256
#define QSTEP (2.0f / 255.0f)

__device__ __forceinline__ float b2f(u16 u) {
  u32 v = ((u32)u) << 16;
  return __builtin_bit_cast(float, v);
}
__device__ __forceinline__ u16 f2b(float f) {
  u32 x = __builtin_bit_cast(u32, f);
  u32 r = (x + 0x7fffu + ((x >> 16) & 1u)) >> 16;  // RNE
  return (u16)r;
}
__device__ __forceinline__ float quantize(float v) {
  v = fminf(fmaxf(v, -1.0f), 1.0f);
  return QSTEP * rintf(v / QSTEP);
}
__device__ __forceinline__ void cp16(const void* g, void* l) {
  __builtin_amdgcn_global_load_lds((__attribute__((address_space(1))) void*)g,
                                   (__attribute__((address_space(3))) void*)l, 16, 0, 0);
}

// ---- per-buffer dtype detect (3 blocks): flag=1 bf16, 0 fp32 ----
__global__ __launch_bounds__(256) void detect3(const u16* __restrict__ a,
                                               const u16* __restrict__ b,
                                               const u16* __restrict__ c, int* flags) {
  const u16* p = (blockIdx.x == 0) ? a : ((blockIdx.x == 1) ? b : c);
  __shared__ int cnt;
  if (threadIdx.x == 0) cnt = 0;
  __syncthreads();
  int n = 0;
#pragma unroll
  for (int i = 0; i < 8; i++) {
    const float v = fabsf(b2f(p[threadIdx.x * 8 + i]));
    if (v > 1e-5f && v < 1e3f) n++;
  }
  atomicAdd(&cnt, n);
  __syncthreads();
  if (threadIdx.x == 0) flags[blockIdx.x] = (cnt > 1536) ? 1 : 0;
}

// ---- fused prep: z=0 transpose w_attn, z=1 transpose w_proj, z=2 convert x ----
__global__ __launch_bounds__(256) void prep_k(const void* __restrict__ x, u16* __restrict__ xb,
                                              const void* __restrict__ wa, u16* __restrict__ wTa,
                                              const void* __restrict__ wp, u16* __restrict__ wTp,
                                              const int* __restrict__ flags) {
  if (blockIdx.z == 2) {  // x: fp32/bf16 -> bf16, vectorized x4
    const int f = flags[0];
    const int nb = gridDim.x * gridDim.y;
    const int bid = blockIdx.y * gridDim.x + blockIdx.x;
    const int n4 = T_SEQ * NC / 4;
    for (int i = bid * 256 + threadIdx.x; i < n4; i += nb * 256) {
      if (f) {
        ((ushort4*)xb)[i] = ((const ushort4*)x)[i];
      } else {
        const float4 v = ((const float4*)x)[i];
        ushort4 o;
        o.x = f2b(v.x); o.y = f2b(v.y); o.z = f2b(v.z); o.w = f2b(v.w);
        ((ushort4*)xb)[i] = o;
      }
    }
    return;
  }
  const int iswp = (blockIdx.z == 1);
  if (iswp && blockIdx.x >= 16) return;
  const void* in = iswp ? wp : wa;
  u16* out = iswp ? wTp : wTa;
  const int Cc = iswp ? 1024 : 3072;
  const int f = flags[iswp ? 2 : 1];
  __shared__ u16 tile[64][65];
  const int tc = blockIdx.x * 64, tr = blockIdx.y * 64;
  const int lx = threadIdx.x & 63, ly = threadIdx.x >> 6;
#pragma unroll
  for (int r = ly; r < 64; r += 4) {
    const long idx = (long)(tr + r) * Cc + tc + lx;
    tile[r][lx] = f ? ((const u16*)in)[idx] : f2b(((const float*)in)[idx]);
  }
  __syncthreads();
#pragma unroll
  for (int r = ly; r < 64; r += 4) out[(tc + r) * 1024 + tr + lx] = tile[lx][r];
}

// ---- 128x128 MFMA GEMM (m97 2-barrier BK=32): C = A[Mx1024] * BT[Nx1024]^T ----
// MODE 0: qkv — XCD swizzle, fused clip+quantize, scatter q/k -> [H][T][HD], v -> [H][HD][T]
// MODE 2: proj split-K — fp32 atomic-accumulate into of[M][NC]
template <int MODE>
__global__ __launch_bounds__(256, 2) void gemm128(const u16* __restrict__ A,
                                                  const u16* __restrict__ BT,
                                                  u16* __restrict__ o0, u16* __restrict__ o1,
                                                  u16* __restrict__ o2, float* __restrict__ of) {
  __shared__ __align__(16) u16 As[4096];  // [kb:4][row:128][8]
  __shared__ __align__(16) u16 Bs[4096];
  const int tid = threadIdx.x;
  const int lane = tid & 63;
  const int wave = tid >> 6;
  const int wr = wave >> 1, wc = wave & 1;
  const int ln15 = lane & 15, lq = lane >> 4;

  int bx = blockIdx.x, by = blockIdx.y;
  if (MODE == 0) {
    // XCD-locality swizzle (grid 24x16, 8 XCDs round-robin on linear wgid):
    // all 24 n-blocks of one A-row-tile land on one XCD -> A re-reads hit local L2.
    const int wg = by * 24 + bx;
    const int xcd = wg & 7, grp = wg >> 3;
    by = xcd * 2 + grp / 24;
    bx = grp % 24;
  }
  const int m0 = by * 128, n0 = bx * 128;
  int kbeg = 0, kend = NC;
  if (MODE == 2) {
    kbeg = blockIdx.z * (NC / 2);
    kend = kbeg + NC / 2;
  }

  const int srow = tid & 127, skb = tid >> 7;
  const u16* ag0 = A + (m0 + srow) * NC + skb * 8;
  const u16* bg0 = BT + (n0 + srow) * NC + skb * 8;
  u16* lA0 = &As[tid * 8];
  u16* lA1 = &As[(tid + 256) * 8];
  u16* lB0 = &Bs[tid * 8];
  u16* lB1 = &Bs[(tid + 256) * 8];

  f32x4 acc[4][4] = {};

  for (int kt = kbeg; kt < kend; kt += 32) {
    cp16(ag0 + kt, lA0);
    cp16(ag0 + kt + 16, lA1);
    cp16(bg0 + kt, lB0);
    cp16(bg0 + kt + 16, lB1);
    __syncthreads();  // staging complete
    bf16x8 af[4], bfr[4];
#pragma unroll
    for (int r = 0; r < 4; r++)
      af[r] = *(const bf16x8*)&As[(lq * 128 + wr * 64 + r * 16 + ln15) * 8];
#pragma unroll
    for (int c = 0; c < 4; c++)
      bfr[c] = *(const bf16x8*)&Bs[(lq * 128 + wc * 64 + c * 16 + ln15) * 8];
#pragma unroll
    for (int r = 0; r < 4; r++)
#pragma unroll
      for (int c = 0; c < 4; c++)
        acc[r][c] = __builtin_amdgcn_mfma_f32_16x16x32_bf16(af[r], bfr[c], acc[r][c], 0, 0, 0);
    __syncthreads();  // reads done before next tile's cp16
  }

  if (MODE == 0) {
#pragma unroll
    for (int c = 0; c < 4; c++) {
      const int gcol = n0 + wc * 64 + c * 16 + ln15;
      const int p = gcol >> 10;  // 0=q, 1=k, 2=v
      const int h = (gcol & 1023) >> 6;
      const int hd = gcol & 63;
#pragma unroll
      for (int r = 0; r < 4; r++) {
        const int rbase = m0 + wr * 64 + r * 16 + lq * 4;
#pragma unroll
        for (int g = 0; g < 4; g++) {
          const u16 b = f2b(quantize(acc[r][c][g]));
          const int row = rbase + g;
          if (p == 0)      o0[(h * T_SEQ + row) * HDIM + hd] = b;
          else if (p == 1) o1[(h * T_SEQ + row) * HDIM + hd] = b;
          else             o2[(h * HDIM + hd) * T_SEQ + row] = b;
        }
      }
    }
  } else {
#pragma unroll
    for (int r = 0; r < 4; r++)
#pragma unroll
      for (int g = 0; g < 4; g++) {
        const int row = m0 + wr * 64 + r * 16 + lq * 4 + g;
#pragma unroll
        for (int c = 0; c < 4; c++)
          __hip_atomic_fetch_add(&of[(long)row * NC + n0 + wc * 64 + c * 16 + ln15],
                                 acc[r][c][g], __ATOMIC_RELAXED, __HIP_MEMORY_SCOPE_AGENT);
      }
  }
}

// ---- attention: one block per (64 queries, head); MFMA QK^T and PV ----
__global__ __launch_bounds__(256) void attn_k(const u16* __restrict__ qh,
                                              const u16* __restrict__ kh,
                                              const u16* __restrict__ vt,
                                              u16* __restrict__ yq) {
  __shared__ __align__(16) u16 S[64 * 328];  // row stride 328 u16 = 656 B (16B-aligned)
  __shared__ float Linv[64];
  const int tid = threadIdx.x;
  const int lane = tid & 63;
  const int wave = tid >> 6;
  const int ln15 = lane & 15, lq = lane >> 4;
  const int i0 = blockIdx.x * 64;
  const int h = blockIdx.y;
  const int j0 = i0 - 256;  // key col c in [0,320) -> j = j0 + c

  const u16* qb = qh + (h * T_SEQ + i0) * HDIM;
  const u16* kb = kh + h * T_SEQ * HDIM;

  bf16x8 qf[4][2];
#pragma unroll
  for (int r = 0; r < 4; r++) {
    qf[r][0] = *(const bf16x8*)&qb[(r * 16 + ln15) * HDIM + lq * 8];
    qf[r][1] = *(const bf16x8*)&qb[(r * 16 + ln15) * HDIM + 32 + lq * 8];
  }

  // phase 1: scores -> mask -> scale -> quantize -> S (masked = -inf)
  for (int ct = wave; ct < 20; ct += 4) {
    const int jt = j0 + ct * 16;
    bf16x8 kf0 = {}, kf1 = {};
    if (jt >= 0) {
      kf0 = *(const bf16x8*)&kb[(jt + ln15) * HDIM + lq * 8];
      kf1 = *(const bf16x8*)&kb[(jt + ln15) * HDIM + 32 + lq * 8];
    }
#pragma unroll
    for (int rt = 0; rt < 4; rt++) {
      const bool skip = (ct < rt) || (ct > rt + 16) || (jt < 0);
      f32x4 s = {0.f, 0.f, 0.f, 0.f};
      if (!skip) {
        s = __builtin_amdgcn_mfma_f32_16x16x32_bf16(qf[rt][0], kf0, s, 0, 0, 0);
        s = __builtin_amdgcn_mfma_f32_16x16x32_bf16(qf[rt][1], kf1, s, 0, 0, 0);
      }
      const int j = jt + ln15;
#pragma unroll
      for (int g = 0; g < 4; g++) {
        const int i = i0 + rt * 16 + lq * 4 + g;
        float v = -INFINITY;
        if (!skip && j <= i && j > i - WINSZ) v = quantize(s[g] * 0.125f);
        S[(rt * 16 + lq * 4 + g) * 328 + ct * 16 + ln15] = f2b(v);
      }
    }
  }
  __syncthreads();

  // phase 2: per-row max + exp (unnormalized) via b128 LDS I/O; Linv[row] = 1/sum
  {
    const int r = tid >> 2, sg = tid & 3;
    u16* Srow = &S[r * 328 + sg * 80];
    uint4 ch[10];
    float m = -INFINITY;
#pragma unroll
    for (int c = 0; c < 10; c++) {
      ch[c] = *(const uint4*)&Srow[c * 8];
      const u32* w = (const u32*)&ch[c];
#pragma unroll
      for (int d = 0; d < 4; d++) {
        m = fmaxf(m, b2f((u16)(w[d] & 0xffffu)));
        m = fmaxf(m, b2f((u16)(w[d] >> 16)));
      }
    }
    m = fmaxf(m, __shfl_xor(m, 1));
    m = fmaxf(m, __shfl_xor(m, 2));
    float l = 0.0f;
#pragma unroll
    for (int c = 0; c < 10; c++) {
      u32* w = (u32*)&ch[c];
#pragma unroll
      for (int d = 0; d < 4; d++) {
        const float e0 = __expf(b2f((u16)(w[d] & 0xffffu)) - m);
        const float e1 = __expf(b2f((u16)(w[d] >> 16)) - m);
        l += e0 + e1;
        w[d] = ((u32)f2b(e1) << 16) | f2b(e0);
      }
      *(uint4*)&Srow[c * 8] = ch[c];
    }
    l += __shfl_xor(l, 1);
    l += __shfl_xor(l, 2);
    if (sg == 0) Linv[r] = 1.0f / l;
  }
  __syncthreads();

  // phase 3: y = (E @ V^T) * Linv ; wave covers hd block = wave*16
  f32x4 acc[4] = {};
  const u16* vb = vt + (h * HDIM + wave * 16 + ln15) * T_SEQ;
  const int kk_lo = (i0 < 256) ? ((256 - i0) >> 5) : 0;  // skip j<0 chunks (E=0 there)
  for (int kk = kk_lo; kk < 10; kk++) {
    const int jb = j0 + kk * 32 + lq * 8;  // >= 0 by kk_lo
    const bf16x8 vf = *(const bf16x8*)&vb[jb];
#pragma unroll
    for (int rt = 0; rt < 4; rt++) {
      const bf16x8 pf = *(const bf16x8*)&S[(rt * 16 + ln15) * 328 + kk * 32 + lq * 8];
      acc[rt] = __builtin_amdgcn_mfma_f32_16x16x32_bf16(pf, vf, acc[rt], 0, 0, 0);
    }
  }
#pragma unroll
  for (int rt = 0; rt < 4; rt++)
#pragma unroll
    for (int g = 0; g < 4; g++) {
      const int row = rt * 16 + lq * 4 + g;
      const int i = i0 + row;
      yq[i * NC + h * HDIM + wave * 16 + ln15] = f2b(quantize(acc[rt][g] * Linv[row]));
    }
}

// ---- launch ----
extern "C" void kernel_launch(void* const* d_in, const int* in_sizes, int n_in,
                              void* d_out, int out_size, void* d_ws, size_t ws_size,
                              hipStream_t stream) {
  // bind by element count (order-robust): x=2M, w_attn=3M, w_proj=1M
  const void *px = d_in[0], *pwa = d_in[1], *pwp = d_in[2];
  for (int i = 0; i < n_in; i++) {
    if (in_sizes[i] == 2048 * 1024) px = d_in[i];
    else if (in_sizes[i] == 3072 * 1024) pwa = d_in[i];
    else if (in_sizes[i] == 1024 * 1024) pwp = d_in[i];
  }

  char* ws = (char*)d_ws;
  int* flags = (int*)ws;                 // [3]: x, w_attn, w_proj
  u16* xb  = (u16*)(ws + (1u << 20));    // [2048][1024]  4 MB
  u16* wTa = (u16*)(ws + (5u << 20));    // [3072][1024]  6 MB
  u16* wTp = (u16*)(ws + (11u << 20));   // [1024][1024]  2 MB
  u16* qh  = (u16*)(ws + (13u << 20));   // [16][2048][64] 4 MB
  u16* kh  = (u16*)(ws + (17u << 20));   // 4 MB
  u16* vt  = (u16*)(ws + (21u << 20));   // [16][64][2048] 4 MB
  u16* yq  = (u16*)(ws + (25u << 20));   // [2048][1024]  4 MB

  detect3<<<3, 256, 0, stream>>>((const u16*)px, (const u16*)pwa, (const u16*)pwp, flags);
  prep_k<<<dim3(48, 16, 3), 256, 0, stream>>>(px, xb, pwa, wTa, pwp, wTp, flags);
  gemm128<0><<<dim3(24, 16), 256, 0, stream>>>(xb, wTa, qh, kh, vt, nullptr);
  attn_k<<<dim3(32, 16), 256, 0, stream>>>(qh, kh, vt, yq);
  hipMemsetAsync(d_out, 0, (size_t)T_SEQ * NC * sizeof(float), stream);
  gemm128<2><<<dim3(8, 16, 2), 256, 0, stream>>>(yq, wTp, nullptr, nullptr, nullptr,
                                                 (float*)d_out);
}

// Round 9
// 165.546 us; speedup vs baseline: 19.5874x; 1.0285x over previous
//
#include <hip/hip_runtime.h>

using u16 = unsigned short;
using u32 = unsigned int;

typedef __bf16 bf16x8 __attribute__((ext_vector_type(8)));
typedef float f32x4 __attribute__((ext_vector_type(4)));

#define T_SEQ 2048
#define NC 1024
#define HDIM 64
#define WINSZ 256
#define QSTEP (2.0f / 255.0f)

__device__ __forceinline__ float b2f(u16 u) {
  u32 v = ((u32)u) << 16;
  return __builtin_bit_cast(float, v);
}
__device__ __forceinline__ u16 f2b(float f) {
  u32 x = __builtin_bit_cast(u32, f);
  u32 r = (x + 0x7fffu + ((x >> 16) & 1u)) >> 16;  // RNE
  return (u16)r;
}
__device__ __forceinline__ float quantize(float v) {
  v = fminf(fmaxf(v, -1.0f), 1.0f);
  return QSTEP * rintf(v / QSTEP);
}
__device__ __forceinline__ void cp16(const void* g, void* l) {
  __builtin_amdgcn_global_load_lds((__attribute__((address_space(1))) void*)g,
                                   (__attribute__((address_space(3))) void*)l, 16, 0, 0);
}

// ---- prep: z=0 transpose w_attn, z=1 transpose w_proj, z=2 convert x (all fp32 -> bf16) ----
__global__ __launch_bounds__(256) void k1_prep(const float* __restrict__ x, u16* __restrict__ xb,
                                               const float* __restrict__ wa, u16* __restrict__ wTa,
                                               const float* __restrict__ wp, u16* __restrict__ wTp) {
  if (blockIdx.z == 2) {  // x convert, vectorized x4, grid-stride
    const int nb = gridDim.x * gridDim.y;
    const int bid = blockIdx.y * gridDim.x + blockIdx.x;
    const int n4 = T_SEQ * NC / 4;
    for (int i = bid * 256 + threadIdx.x; i < n4; i += nb * 256) {
      const float4 v = ((const float4*)x)[i];
      ushort4 o;
      o.x = f2b(v.x); o.y = f2b(v.y); o.z = f2b(v.z); o.w = f2b(v.w);
      ((ushort4*)xb)[i] = o;
    }
    return;
  }
  const int iswp = (blockIdx.z == 1);
  if (iswp && blockIdx.x >= 16) return;
  const float* in = iswp ? wp : wa;
  u16* out = iswp ? wTp : wTa;
  const int Cc = iswp ? 1024 : 3072;
  __shared__ u16 tile[64][65];
  const int tc = blockIdx.x * 64, tr = blockIdx.y * 64;
  const int lx = threadIdx.x & 63, ly = threadIdx.x >> 6;
#pragma unroll
  for (int r = ly; r < 64; r += 4)
    tile[r][lx] = f2b(in[(long)(tr + r) * Cc + tc + lx]);
  __syncthreads();
#pragma unroll
  for (int r = ly; r < 64; r += 4) out[(tc + r) * 1024 + tr + lx] = tile[lx][r];
}

// ---- qkv GEMM: 128x128 tile, BK=64 single-buffer (16 iters), XCD swizzle ----
// C = xb[2048x1024] * wTa[3072x1024]^T ; fused clip+quantize scatter:
// q -> o0[H][T][HD], k -> o1[H][T][HD], v -> o2[H][HD][T]
__global__ __launch_bounds__(256, 2) void k2_qkv(const u16* __restrict__ A,
                                                 const u16* __restrict__ BT,
                                                 u16* __restrict__ o0, u16* __restrict__ o1,
                                                 u16* __restrict__ o2) {
  __shared__ __align__(16) u16 As[8192];  // [kc:8][row:128][8]
  __shared__ __align__(16) u16 Bs[8192];
  const int tid = threadIdx.x;
  const int lane = tid & 63;
  const int wave = tid >> 6;
  const int wr = wave >> 1, wc = wave & 1;
  const int ln15 = lane & 15, lq = lane >> 4;

  // XCD-locality swizzle (grid 24x16; 8 XCDs round-robin on linear wgid)
  const int wg = blockIdx.y * 24 + blockIdx.x;
  const int xcd = wg & 7, grp = wg >> 3;
  const int by = xcd * 2 + grp / 24;
  const int bx = grp % 24;
  const int m0 = by * 128, n0 = bx * 128;

  // staging: 1024 16B chunks/matrix/tile; 4 per thread. id -> kc=id>>7, row=id&127
  const u16* ag[4];
  const u16* bg[4];
  u16* la[4];
  u16* lb[4];
#pragma unroll
  for (int i = 0; i < 4; i++) {
    const int id = tid + i * 256;
    const int kc = id >> 7, row = id & 127;
    ag[i] = A + (m0 + row) * NC + kc * 8;
    bg[i] = BT + (n0 + row) * NC + kc * 8;
    la[i] = &As[id * 8];
    lb[i] = &Bs[id * 8];
  }

  f32x4 acc[4][4] = {};

  for (int kt = 0; kt < NC; kt += 64) {
#pragma unroll
    for (int i = 0; i < 4; i++) {
      cp16(ag[i] + kt, la[i]);
      cp16(bg[i] + kt, lb[i]);
    }
    __syncthreads();  // staging complete
#pragma unroll
    for (int s = 0; s < 2; s++) {
      const int kc = s * 4 + lq;
      bf16x8 af[4], bfr[4];
#pragma unroll
      for (int r = 0; r < 4; r++)
        af[r] = *(const bf16x8*)&As[(kc * 128 + wr * 64 + r * 16 + ln15) * 8];
#pragma unroll
      for (int c = 0; c < 4; c++)
        bfr[c] = *(const bf16x8*)&Bs[(kc * 128 + wc * 64 + c * 16 + ln15) * 8];
#pragma unroll
      for (int r = 0; r < 4; r++)
#pragma unroll
        for (int c = 0; c < 4; c++)
          acc[r][c] = __builtin_amdgcn_mfma_f32_16x16x32_bf16(af[r], bfr[c], acc[r][c], 0, 0, 0);
    }
    __syncthreads();  // all reads done before next tile's cp16
  }

#pragma unroll
  for (int c = 0; c < 4; c++) {
    const int gcol = n0 + wc * 64 + c * 16 + ln15;
    const int p = gcol >> 10;  // 0=q, 1=k, 2=v
    const int h = (gcol & 1023) >> 6;
    const int hd = gcol & 63;
#pragma unroll
    for (int r = 0; r < 4; r++) {
      const int rbase = m0 + wr * 64 + r * 16 + lq * 4;
#pragma unroll
      for (int g = 0; g < 4; g++) {
        const u16 b = f2b(quantize(acc[r][c][g]));
        const int row = rbase + g;
        if (p == 0)      o0[(h * T_SEQ + row) * HDIM + hd] = b;
        else if (p == 1) o1[(h * T_SEQ + row) * HDIM + hd] = b;
        else             o2[(h * HDIM + hd) * T_SEQ + row] = b;
      }
    }
  }
}

// ---- attention: one block per (64 queries, head); MFMA QK^T and PV ----
__global__ __launch_bounds__(256) void k3_attn(const u16* __restrict__ qh,
                                               const u16* __restrict__ kh,
                                               const u16* __restrict__ vt,
                                               u16* __restrict__ yq) {
  __shared__ __align__(16) u16 S[64 * 328];  // row stride 328 u16 = 656 B
  __shared__ float Linv[64];
  const int tid = threadIdx.x;
  const int lane = tid & 63;
  const int wave = tid >> 6;
  const int ln15 = lane & 15, lq = lane >> 4;
  const int i0 = blockIdx.x * 64;
  const int h = blockIdx.y;
  const int j0 = i0 - 256;  // key col c in [0,320) -> j = j0 + c

  const u16* qb = qh + (h * T_SEQ + i0) * HDIM;
  const u16* kb = kh + h * T_SEQ * HDIM;

  bf16x8 qf[4][2];
#pragma unroll
  for (int r = 0; r < 4; r++) {
    qf[r][0] = *(const bf16x8*)&qb[(r * 16 + ln15) * HDIM + lq * 8];
    qf[r][1] = *(const bf16x8*)&qb[(r * 16 + ln15) * HDIM + 32 + lq * 8];
  }

  // prefetch all K fragments for this wave's 5 column-tiles
  bf16x8 kf[5][2];
#pragma unroll
  for (int t = 0; t < 5; t++) {
    const int jt = j0 + (wave + t * 4) * 16;
    if (jt >= 0) {
      kf[t][0] = *(const bf16x8*)&kb[(jt + ln15) * HDIM + lq * 8];
      kf[t][1] = *(const bf16x8*)&kb[(jt + ln15) * HDIM + 32 + lq * 8];
    } else {
      kf[t][0] = bf16x8{};
      kf[t][1] = bf16x8{};
    }
  }

  // phase 1: scores -> mask -> scale -> quantize -> S (masked = -inf)
#pragma unroll
  for (int t = 0; t < 5; t++) {
    const int ct = wave + t * 4;
    const int jt = j0 + ct * 16;
#pragma unroll
    for (int rt = 0; rt < 4; rt++) {
      const bool skip = (ct < rt) || (ct > rt + 16) || (jt < 0);
      f32x4 s = {0.f, 0.f, 0.f, 0.f};
      if (!skip) {
        s = __builtin_amdgcn_mfma_f32_16x16x32_bf16(qf[rt][0], kf[t][0], s, 0, 0, 0);
        s = __builtin_amdgcn_mfma_f32_16x16x32_bf16(qf[rt][1], kf[t][1], s, 0, 0, 0);
      }
      const int j = jt + ln15;
#pragma unroll
      for (int g = 0; g < 4; g++) {
        const int i = i0 + rt * 16 + lq * 4 + g;
        float v = -INFINITY;
        if (!skip && j <= i && j > i - WINSZ) v = quantize(s[g] * 0.125f);
        S[(rt * 16 + lq * 4 + g) * 328 + ct * 16 + ln15] = f2b(v);
      }
    }
  }
  __syncthreads();

  // phase 2: per-row max + unnormalized exp via b128 LDS I/O; Linv[row] = 1/sum
  {
    const int r = tid >> 2, sg = tid & 3;
    u16* Srow = &S[r * 328 + sg * 80];
    uint4 ch[10];
    float m = -INFINITY;
#pragma unroll
    for (int c = 0; c < 10; c++) {
      ch[c] = *(const uint4*)&Srow[c * 8];
      const u32* w = (const u32*)&ch[c];
#pragma unroll
      for (int d = 0; d < 4; d++) {
        m = fmaxf(m, b2f((u16)(w[d] & 0xffffu)));
        m = fmaxf(m, b2f((u16)(w[d] >> 16)));
      }
    }
    m = fmaxf(m, __shfl_xor(m, 1));
    m = fmaxf(m, __shfl_xor(m, 2));
    float l = 0.0f;
#pragma unroll
    for (int c = 0; c < 10; c++) {
      u32* w = (u32*)&ch[c];
#pragma unroll
      for (int d = 0; d < 4; d++) {
        const float e0 = __expf(b2f((u16)(w[d] & 0xffffu)) - m);
        const float e1 = __expf(b2f((u16)(w[d] >> 16)) - m);
        l += e0 + e1;
        w[d] = ((u32)f2b(e1) << 16) | f2b(e0);
      }
      *(uint4*)&Srow[c * 8] = ch[c];
    }
    l += __shfl_xor(l, 1);
    l += __shfl_xor(l, 2);
    if (sg == 0) Linv[r] = 1.0f / l;
  }
  __syncthreads();

  // phase 3: y = (E @ V^T) * Linv ; wave covers hd block = wave*16; prefetch V
  const u16* vb = vt + (h * HDIM + wave * 16 + ln15) * T_SEQ;
  bf16x8 vf[10];
#pragma unroll
  for (int kk = 0; kk < 10; kk++) {
    int jb = j0 + kk * 32 + lq * 8;
    if (jb < 0) jb = 0;  // unused when masked; keep load in-bounds
    vf[kk] = *(const bf16x8*)&vb[jb];
  }
  f32x4 acc[4] = {};
  const int kk_lo = (i0 < 256) ? ((256 - i0) >> 5) : 0;  // skip j<0 chunks (E=0 there)
  for (int kk = kk_lo; kk < 10; kk++) {
#pragma unroll
    for (int rt = 0; rt < 4; rt++) {
      const bf16x8 pf = *(const bf16x8*)&S[(rt * 16 + ln15) * 328 + kk * 32 + lq * 8];
      acc[rt] = __builtin_amdgcn_mfma_f32_16x16x32_bf16(pf, vf[kk], acc[rt], 0, 0, 0);
    }
  }
#pragma unroll
  for (int rt = 0; rt < 4; rt++)
#pragma unroll
    for (int g = 0; g < 4; g++) {
      const int row = rt * 16 + lq * 4 + g;
      const int i = i0 + row;
      yq[i * NC + h * HDIM + wave * 16 + ln15] = f2b(quantize(acc[rt][g] * Linv[row]));
    }
}

// ---- proj GEMM: 64x64 tile, BK=64, grid (16,32)=512 blocks, fp32 store ----
__global__ __launch_bounds__(256, 4) void k4_proj(const u16* __restrict__ A,
                                                  const u16* __restrict__ BT,
                                                  float* __restrict__ of) {
  __shared__ __align__(16) u16 As[4096];  // [kc:8][row:64][8]
  __shared__ __align__(16) u16 Bs[4096];
  const int tid = threadIdx.x;
  const int lane = tid & 63;
  const int wave = tid >> 6;
  const int wr = wave >> 1, wc = wave & 1;
  const int ln15 = lane & 15, lq = lane >> 4;
  const int m0 = blockIdx.y * 64, n0 = blockIdx.x * 64;

  // staging: 512 16B chunks/matrix/tile; 2 per thread. id -> kc=id>>6, row=id&63
  const u16* ag[2];
  const u16* bg[2];
  u16* la[2];
  u16* lb[2];
#pragma unroll
  for (int i = 0; i < 2; i++) {
    const int id = tid + i * 256;
    const int kc = id >> 6, row = id & 63;
    ag[i] = A + (m0 + row) * NC + kc * 8;
    bg[i] = BT + (n0 + row) * NC + kc * 8;
    la[i] = &As[id * 8];
    lb[i] = &Bs[id * 8];
  }

  f32x4 acc[2][2] = {};

  for (int kt = 0; kt < NC; kt += 64) {
#pragma unroll
    for (int i = 0; i < 2; i++) {
      cp16(ag[i] + kt, la[i]);
      cp16(bg[i] + kt, lb[i]);
    }
    __syncthreads();
#pragma unroll
    for (int s = 0; s < 2; s++) {
      const int kc = s * 4 + lq;
      bf16x8 af[2], bfr[2];
#pragma unroll
      for (int r = 0; r < 2; r++)
        af[r] = *(const bf16x8*)&As[(kc * 64 + wr * 32 + r * 16 + ln15) * 8];
#pragma unroll
      for (int c = 0; c < 2; c++)
        bfr[c] = *(const bf16x8*)&Bs[(kc * 64 + wc * 32 + c * 16 + ln15) * 8];
#pragma unroll
      for (int r = 0; r < 2; r++)
#pragma unroll
        for (int c = 0; c < 2; c++)
          acc[r][c] = __builtin_amdgcn_mfma_f32_16x16x32_bf16(af[r], bfr[c], acc[r][c], 0, 0, 0);
    }
    __syncthreads();
  }

#pragma unroll
  for (int r = 0; r < 2; r++)
#pragma unroll
    for (int g = 0; g < 4; g++) {
      const int row = m0 + wr * 32 + r * 16 + lq * 4 + g;
#pragma unroll
      for (int c = 0; c < 2; c++)
        of[(long)row * NC + n0 + wc * 32 + c * 16 + ln15] = acc[r][c][g];
    }
}

// ---- launch ----
extern "C" void kernel_launch(void* const* d_in, const int* in_sizes, int n_in,
                              void* d_out, int out_size, void* d_ws, size_t ws_size,
                              hipStream_t stream) {
  // bind by element count (order-robust): x=2M, w_attn=3M, w_proj=1M; dtype fp32 (proven R1-R5)
  const void *px = d_in[0], *pwa = d_in[1], *pwp = d_in[2];
  for (int i = 0; i < n_in; i++) {
    if (in_sizes[i] == 2048 * 1024) px = d_in[i];
    else if (in_sizes[i] == 3072 * 1024) pwa = d_in[i];
    else if (in_sizes[i] == 1024 * 1024) pwp = d_in[i];
  }

  char* ws = (char*)d_ws;
  u16* xb  = (u16*)(ws + (1u << 20));    // [2048][1024]  4 MB
  u16* wTa = (u16*)(ws + (5u << 20));    // [3072][1024]  6 MB
  u16* wTp = (u16*)(ws + (11u << 20));   // [1024][1024]  2 MB
  u16* qh  = (u16*)(ws + (13u << 20));   // [16][2048][64] 4 MB
  u16* kh  = (u16*)(ws + (17u << 20));   // 4 MB
  u16* vt  = (u16*)(ws + (21u << 20));   // [16][64][2048] 4 MB
  u16* yq  = (u16*)(ws + (25u << 20));   // [2048][1024]  4 MB

  k1_prep<<<dim3(48, 16, 3), 256, 0, stream>>>((const float*)px, xb, (const float*)pwa, wTa,
                                               (const float*)pwp, wTp);
  k2_qkv<<<dim3(24, 16), 256, 0, stream>>>(xb, wTa, qh, kh, vt);
  k3_attn<<<dim3(32, 16), 256, 0, stream>>>(qh, kh, vt, yq);
  k4_proj<<<dim3(16, 32), 256, 0, stream>>>(yq, wTp, (float*)d_out);
}